// Round 10
// baseline (495.363 us; speedup 1.0000x reference)
//
#include <hip/hip_runtime.h>

#define NEGV (-1e9f)

typedef short s16x8 __attribute__((ext_vector_type(8)));
typedef float f32x4 __attribute__((ext_vector_type(4)));

__device__ __forceinline__ float ftanh(float x) {
    float e = __expf(2.f * x);
    return 1.f - 2.f * __builtin_amdgcn_rcpf(e + 1.f);
}

__device__ __forceinline__ unsigned short f2bf(float f) {
    unsigned u = __float_as_uint(f);
    u = u + 0x7FFFu + ((u >> 16) & 1u);
    return (unsigned short)(u >> 16);
}

__device__ __forceinline__ float bf2f(unsigned short u) {
    return __uint_as_float(((unsigned)u) << 16);
}

// W (256x256 f32, row=k, col=out) -> B-fragment-ordered bf16.
__global__ __launch_bounds__(256) void wprep_kernel(
    const float* __restrict__ W0, const float* __restrict__ W1, const float* __restrict__ W2,
    unsigned short* __restrict__ O0, unsigned short* __restrict__ O1, unsigned short* __restrict__ O2)
{
    const float* W = blockIdx.y == 0 ? W0 : (blockIdx.y == 1 ? W1 : W2);
    unsigned short* O = blockIdx.y == 0 ? O0 : (blockIdx.y == 1 ? O1 : O2);
    int slot = blockIdx.x * 256 + threadIdx.x;   // 0..8191
    int lane = slot & 63;
    int kk   = (slot >> 6) & 7;
    int nblk = slot >> 9;
    int col  = nblk * 16 + (lane & 15);
    int k0   = kk * 32 + (lane >> 4) * 8;
    s16x8 v;
    #pragma unroll
    for (int j = 0; j < 8; ++j) v[j] = (short)f2bf(W[(k0 + j) * 256 + col]);
    ((s16x8*)O)[slot] = v;
}

// All 4 pools' tiles in ONE dispatch, register-pipelined: while computing
// tile k (MFMA + epilogue + tile-softmax + weighted sum), the 16 float4
// loads of tile k+1 are already in flight (T14 issue-early / write-late).
// Grid = 512 WGs x 7 tiles = 3584 = token 2048 + graph/anchor/neg 512 each.
__global__ __launch_bounds__(256) void fused_sp_kernel(
    const float* __restrict__ f0, const int* __restrict__ m0,
    const float* __restrict__ f1, const int* __restrict__ m1,
    const float* __restrict__ f2, const int* __restrict__ m2,
    const float* __restrict__ f3, const int* __restrict__ m3,
    const unsigned short* __restrict__ wbT, const unsigned short* __restrict__ wbG,
    const unsigned short* __restrict__ wbD,
    const float* __restrict__ bt, const float* __restrict__ vt, const float* __restrict__ ct,
    const float* __restrict__ bg, const float* __restrict__ vg, const float* __restrict__ cg,
    const float* __restrict__ bd, const float* __restrict__ vd, const float* __restrict__ cd,
    float* __restrict__ pT, float* __restrict__ pG,
    float* __restrict__ pA, float* __restrict__ pN)
{
    __shared__ char  ldsA[64 * 512];   // 64 pos x 256 bf16, XOR-swizzled
    __shared__ float red[256];
    __shared__ float s_lds[64];
    __shared__ float msk_lds[64];
    __shared__ float p_lds[64];
    __shared__ float pbuf[1024];
    const int t = threadIdx.x;
    const int w = t >> 6, lane = t & 63;
    const int g = lane >> 4, li = lane & 15;

    // next-tile context (written by resolve)
    const float* fp; const int* mp_n; const s16x8* wb_n;
    const float *bi_n, *vv_n, *cc_n; float* gp_n; int pret_n;

    auto resolve = [&](int tile) {
        int b, tix, S; const float* fb; const int* mb;
        if (tile < 2048)      { b = tile >> 5;            tix = tile & 31; S = 2048;
            fb = f0; mb = m0; wb_n = (const s16x8*)wbT; bi_n = bt; vv_n = vt; cc_n = ct;
            gp_n = pT + ((size_t)b * 32 + tix) * 260; pret_n = 0; }
        else if (tile < 2560) { int l = tile - 2048; b = l >> 3; tix = l & 7; S = 512;
            fb = f1; mb = m1; wb_n = (const s16x8*)wbG; bi_n = bg; vv_n = vg; cc_n = cg;
            gp_n = pG + ((size_t)b * 8 + tix) * 260; pret_n = 1; }
        else if (tile < 3072) { int l = tile - 2560; b = l >> 3; tix = l & 7; S = 512;
            fb = f2; mb = m2; wb_n = (const s16x8*)wbD; bi_n = bd; vv_n = vd; cc_n = cd;
            gp_n = pA + ((size_t)b * 8 + tix) * 260; pret_n = 0; }
        else                  { int l = tile - 3072; b = l >> 3; tix = l & 7; S = 512;
            fb = f3; mb = m3; wb_n = (const s16x8*)wbD; bi_n = bd; vv_n = vd; cc_n = cd;
            gp_n = pN + ((size_t)b * 8 + tix) * 260; pret_n = 0; }
        fp   = fb + ((size_t)b * S + tix * 64) * 256;
        mp_n = mb + (size_t)b * S + tix * 64;
    };

    float4 r[16];
    auto load16 = [&]() {
        const float4* f4 = (const float4*)fp;
        #pragma unroll
        for (int i = 0; i < 8; ++i) {
            int chunk = t + i * 256;
            r[2 * i]     = f4[chunk * 2];
            r[2 * i + 1] = f4[chunk * 2 + 1];
        }
    };

    resolve(blockIdx.x);
    int pret = pret_n; const int* mp = mp_n; const s16x8* wb = wb_n;
    const float *bi = bi_n, *vv = vv_n, *cc = cc_n; float* gp = gp_n;
    load16();

    for (int k = 0; k < 7; ++k) {
        // ---- convert staged regs (tile k) -> bf16 LDS ----
        #pragma unroll
        for (int i = 0; i < 8; ++i) {
            int chunk = t + i * 256;
            int row = chunk >> 5;
            int col16 = chunk & 31;
            float4 fa = r[2 * i], fb4 = r[2 * i + 1];
            if (pret) {
                fa.x = ftanh(fa.x); fa.y = ftanh(fa.y); fa.z = ftanh(fa.z); fa.w = ftanh(fa.w);
                fb4.x = ftanh(fb4.x); fb4.y = ftanh(fb4.y); fb4.z = ftanh(fb4.z); fb4.w = ftanh(fb4.w);
            }
            s16x8 pk;
            pk[0] = (short)f2bf(fa.x); pk[1] = (short)f2bf(fa.y);
            pk[2] = (short)f2bf(fa.z); pk[3] = (short)f2bf(fa.w);
            pk[4] = (short)f2bf(fb4.x); pk[5] = (short)f2bf(fb4.y);
            pk[6] = (short)f2bf(fb4.z); pk[7] = (short)f2bf(fb4.w);
            int addr = (row * 512 + col16 * 16) ^ ((row & 7) << 4);
            *(s16x8*)(ldsA + addr) = pk;
        }
        // ---- issue next tile's loads (in flight during compute below) ----
        if (k < 6) { resolve(blockIdx.x + (k + 1) * 512); load16(); }
        __syncthreads();

        // ---- MFMA: A = feat rows (M=64), wave w owns cols w*64..w*64+63 ----
        f32x4 acc[4][4];
        #pragma unroll
        for (int m = 0; m < 4; ++m)
            #pragma unroll
            for (int n = 0; n < 4; ++n)
                acc[m][n] = (f32x4)0.f;
        #pragma unroll
        for (int kk = 0; kk < 8; ++kk) {
            s16x8 a[4];
            #pragma unroll
            for (int m = 0; m < 4; ++m) {
                int row = m * 16 + li;
                int addr = (row * 512 + kk * 64 + g * 16) ^ ((row & 7) << 4);
                a[m] = *(const s16x8*)(ldsA + addr);
            }
            #pragma unroll
            for (int n = 0; n < 4; ++n) {
                s16x8 bfr = wb[((w * 4 + n) * 8 + kk) * 64 + lane];
                #pragma unroll
                for (int m = 0; m < 4; ++m)
                    acc[m][n] = __builtin_amdgcn_mfma_f32_16x16x32_bf16(a[m], bfr, acc[m][n], 0, 0, 0);
            }
        }

        // ---- scores: sum_cols tanh(x+bias)*v (D: col=lane&15, row=g*4+reg) ----
        float bil[4], vvl[4];
        #pragma unroll
        for (int n = 0; n < 4; ++n) {
            int col = w * 64 + n * 16 + li;
            bil[n] = bi[col]; vvl[n] = vv[col];
        }
        #pragma unroll
        for (int m = 0; m < 4; ++m) {
            #pragma unroll
            for (int reg = 0; reg < 4; ++reg) {
                float val = 0.f;
                #pragma unroll
                for (int n = 0; n < 4; ++n)
                    val += ftanh(acc[m][n][reg] + bil[n]) * vvl[n];
                val += __shfl_xor(val, 1);
                val += __shfl_xor(val, 2);
                val += __shfl_xor(val, 4);
                val += __shfl_xor(val, 8);
                if (li == 0) red[(m * 16 + g * 4 + reg) * 4 + w] = val;
            }
        }
        __syncthreads();
        if (t < 64) {
            float sc = red[t * 4] + red[t * 4 + 1] + red[t * 4 + 2] + red[t * 4 + 3] + cc[0];
            int mk = mp[t];
            s_lds[t]   = mk ? sc : NEGV;
            msk_lds[t] = mk ? 1.f : 0.f;
        }
        __syncthreads();

        // ---- tile softmax (all waves identical) ----
        float sl = s_lds[lane], ml = msk_lds[lane];
        float mt = sl;
        #pragma unroll
        for (int o = 1; o < 64; o <<= 1) mt = fmaxf(mt, __shfl_xor(mt, o));
        float p = __expf(sl - mt) * ml;
        float lsum = p;
        #pragma unroll
        for (int o = 1; o < 64; o <<= 1) lsum += __shfl_xor(lsum, o);
        if (w == 0) p_lds[lane] = p;
        __syncthreads();

        // ---- weighted sum: wave w covers s in [w*16,w*16+16) ----
        float2 wacc[2];
        wacc[0] = make_float2(0.f, 0.f); wacc[1] = make_float2(0.f, 0.f);
        #pragma unroll
        for (int hb = 0; hb < 2; ++hb) {
            #pragma unroll
            for (int j = 0; j < 16; ++j) {
                int s = w * 16 + j;
                float ps = p_lds[s];
                int byte = (s * 512 + hb * 256 + lane * 4) ^ ((s & 7) << 4);
                unsigned pair = *(const unsigned*)(ldsA + byte);
                wacc[hb].x += ps * bf2f((unsigned short)(pair & 0xffffu));
                wacc[hb].y += ps * bf2f((unsigned short)(pair >> 16));
            }
        }
        #pragma unroll
        for (int hb = 0; hb < 2; ++hb)
            *(float2*)&pbuf[w * 256 + hb * 128 + lane * 2] = wacc[hb];
        __syncthreads();   // after this barrier ldsA / pbuf reads are done -> safe to restage

        gp[t] = pbuf[t] + pbuf[256 + t] + pbuf[512 + t] + pbuf[768 + t];
        if (t == 0) { gp[256] = mt; gp[257] = lsum; }

        // adopt next tile's context
        pret = pret_n; mp = mp_n; wb = wb_n; bi = bi_n; vv = vv_n; cc = cc_n; gp = gp_n;
    }
}

// Merge tile partials with max-rescaling.
__global__ __launch_bounds__(256) void combine_kernel(
    const float* __restrict__ pt_t, const float* __restrict__ pt_g,
    const float* __restrict__ pt_a, const float* __restrict__ pt_n,
    float* __restrict__ po_t, float* __restrict__ po_g,
    float* __restrict__ po_a, float* __restrict__ po_n)
{
    const int pool = blockIdx.y, b = blockIdx.x, t = threadIdx.x;
    const float* pb; float* out; int T;
    if      (pool == 0) { pb = pt_t; out = po_t; T = 32; }
    else if (pool == 1) { pb = pt_g; out = po_g; T = 8;  }
    else if (pool == 2) { pb = pt_a; out = po_a; T = 8;  }
    else                { pb = pt_n; out = po_n; T = 8;  }
    pb += (size_t)b * T * 260;

    float mg = -3e38f;
    for (int k = 0; k < T; ++k) mg = fmaxf(mg, pb[k * 260 + 256]);
    float lg = 0.f, acc = 0.f;
    for (int k = 0; k < T; ++k) {
        float sc = __expf(pb[k * 260 + 256] - mg);
        lg  += pb[k * 260 + 257] * sc;
        acc += pb[k * 260 + t] * sc;
    }
    out[b * 256 + t] = acc / lg;
}

__global__ __launch_bounds__(256) void code_kernel(
    const float* __restrict__ pool_t, const float* __restrict__ pool_g,
    const float* __restrict__ Wf, const float* __restrict__ bf,
    float* __restrict__ code)
{
    __shared__ float cat[512];
    const int t = threadIdx.x, b = blockIdx.x;
    cat[t]       = ftanh(pool_t[b * 256 + t]);
    cat[t + 256] = ftanh(pool_g[b * 256 + t]);
    __syncthreads();
    float sum = bf[t];
    for (int i = 0; i < 512; ++i) sum += cat[i] * Wf[i * 256 + t];
    code[b * 256 + t] = ftanh(sum);
}

__global__ __launch_bounds__(256) void loss_kernel(
    const float* __restrict__ code, const float* __restrict__ pool_a,
    const float* __restrict__ pool_n, float* __restrict__ out)
{
    __shared__ float wred[4];
    const int t = threadIdx.x, wave = t >> 6, lane = t & 63;
    float wloss = 0.f;
    for (int b = wave; b < 64; b += 4) {
        float4 c4 = ((const float4*)code)[b * 64 + lane];
        float4 a4 = ((const float4*)pool_a)[b * 64 + lane];
        float4 n4 = ((const float4*)pool_n)[b * 64 + lane];
        a4.x = ftanh(ftanh(a4.x)); a4.y = ftanh(ftanh(a4.y));
        a4.z = ftanh(ftanh(a4.z)); a4.w = ftanh(ftanh(a4.w));
        n4.x = ftanh(ftanh(n4.x)); n4.y = ftanh(ftanh(n4.y));
        n4.z = ftanh(ftanh(n4.z)); n4.w = ftanh(ftanh(n4.w));
        float dca = c4.x * a4.x + c4.y * a4.y + c4.z * a4.z + c4.w * a4.w;
        float dcn = c4.x * n4.x + c4.y * n4.y + c4.z * n4.z + c4.w * n4.w;
        float dcc = c4.x * c4.x + c4.y * c4.y + c4.z * c4.z + c4.w * c4.w;
        float daa = a4.x * a4.x + a4.y * a4.y + a4.z * a4.z + a4.w * a4.w;
        float dnn = n4.x * n4.x + n4.y * n4.y + n4.z * n4.z + n4.w * n4.w;
        #pragma unroll
        for (int o = 32; o > 0; o >>= 1) {
            dca += __shfl_down(dca, o);
            dcn += __shfl_down(dcn, o);
            dcc += __shfl_down(dcc, o);
            daa += __shfl_down(daa, o);
            dnn += __shfl_down(dnn, o);
        }
        if (lane == 0) {
            float ca = dca / fmaxf(sqrtf(dcc) * sqrtf(daa), 1e-8f);
            float cn = dcn / fmaxf(sqrtf(dcc) * sqrtf(dnn), 1e-8f);
            wloss += fmaxf(0.6f - ca + cn, 0.f);
        }
    }
    if (lane == 0) wred[wave] = wloss;
    __syncthreads();
    if (t == 0) out[0] = (wred[0] + wred[1] + wred[2] + wred[3]) * (1.f / 64.f);
}

extern "C" void kernel_launch(void* const* d_in, const int* in_sizes, int n_in,
                              void* d_out, int out_size, void* d_ws, size_t ws_size,
                              hipStream_t stream) {
    const float* token_feat = (const float*)d_in[0];
    const int*   token_mask = (const int*)d_in[1];
    const float* graph_feat = (const float*)d_in[2];
    const int*   graph_mask = (const int*)d_in[3];
    const float* da_feat    = (const float*)d_in[4];
    const int*   da_mask    = (const int*)d_in[5];
    const float* dn_feat    = (const float*)d_in[6];
    const int*   dn_mask    = (const int*)d_in[7];
    const float* Wt = (const float*)d_in[8];
    const float* bt = (const float*)d_in[9];
    const float* vt = (const float*)d_in[10];
    const float* ct = (const float*)d_in[11];
    const float* Wg = (const float*)d_in[12];
    const float* bg = (const float*)d_in[13];
    const float* vg = (const float*)d_in[14];
    const float* cg = (const float*)d_in[15];
    const float* Wd = (const float*)d_in[16];
    const float* bd = (const float*)d_in[17];
    const float* vd = (const float*)d_in[18];
    const float* cd = (const float*)d_in[19];
    const float* Wf = (const float*)d_in[20];
    const float* bf = (const float*)d_in[21];

    float* ws   = (float*)d_ws;
    float* pt_t = ws;                        // 64*32*260
    float* pt_g = pt_t + 64 * 32 * 260;      // 64*8*260 each
    float* pt_a = pt_g + 64 * 8 * 260;
    float* pt_n = pt_a + 64 * 8 * 260;
    float* po_t = pt_n + 64 * 8 * 260;       // 64*256 each
    float* po_g = po_t + 64 * 256;
    float* po_a = po_g + 64 * 256;
    float* po_n = po_a + 64 * 256;
    float* code = po_n + 64 * 256;
    unsigned short* wb_t = (unsigned short*)(code + 64 * 256);  // 65536 bf16 each
    unsigned short* wb_g = wb_t + 65536;
    unsigned short* wb_d = wb_g + 65536;

    wprep_kernel<<<dim3(32, 3), 256, 0, stream>>>(Wt, Wg, Wd, wb_t, wb_g, wb_d);

    fused_sp_kernel<<<512, 256, 0, stream>>>(
        token_feat, token_mask, graph_feat, graph_mask,
        da_feat, da_mask, dn_feat, dn_mask,
        wb_t, wb_g, wb_d,
        bt, vt, ct, bg, vg, cg, bd, vd, cd,
        pt_t, pt_g, pt_a, pt_n);

    combine_kernel<<<dim3(64, 4), 256, 0, stream>>>(pt_t, pt_g, pt_a, pt_n, po_t, po_g, po_a, po_n);

    code_kernel<<<64, 256, 0, stream>>>(po_t, po_g, Wf, bf, code);
    loss_kernel<<<1, 256, 0, stream>>>(code, po_a, po_n, (float*)d_out);
}